// Round 1
// baseline (2101.041 us; speedup 1.0000x reference)
//
#include <hip/hip_runtime.h>
#include <math.h>

// Problem constants
#define B_    32
#define NR_   4096
#define DIN_  384
#define DCTX_ 128
#define H__   64
#define A__   16

__device__ __forceinline__ float frelu(float x) { return fmaxf(x, 0.0f); }

// ---------------------------------------------------------------------------
// K1: fused VAE. grid = (B*NR)/64 = 2048 blocks, 256 threads.
// Each block handles a 64-row tile. Thread grid 16x16, each thread a 4x4 tile.
// ---------------------------------------------------------------------------
struct alignas(16) Smem {
  union {
    struct { float As[32][68]; float Bs[32][68]; } p1;  // phase-1 GEMM staging
    float zT[64][68];                                   // z transposed (k-major)
  } u;
  float hT[64][68];     // h transposed; reused as tT in phase 3
  float rsq[16][68];    // per-row z^2 partials (by tx)
  float nrm[64];        // row norms of z
  double red[256];      // block reduction
};

__global__ __launch_bounds__(256)
void vae_kernel(const float* __restrict__ roles,
                const float* __restrict__ eps,
                const float* __restrict__ W1,  const float* __restrict__ b1,
                const float* __restrict__ W21, const float* __restrict__ b21,
                const float* __restrict__ W22, const float* __restrict__ b22,
                const float* __restrict__ W3,  const float* __restrict__ b3,
                const float* __restrict__ W4,  const float* __restrict__ b4,
                float* __restrict__ emb, double* __restrict__ sums) {
  __shared__ Smem s;
  const int tid = threadIdx.x;
  const int tx = tid & 15, ty = tid >> 4;
  const int r0 = ty * 4, c0 = tx * 4;
  const long row_base = (long)blockIdx.x * 64;

  // ---------------- Phase 1: h = relu(roles @ W1 + b1), K = 384 ----------------
  float acc[4][4];
#pragma unroll
  for (int i = 0; i < 4; i++)
#pragma unroll
    for (int j = 0; j < 4; j++) acc[i][j] = 0.0f;

  const int lr  = tid >> 2;          // 0..63  (roles row within tile)
  const int lk0 = (tid & 3) * 8;     // 0,8,16,24 (k offset)
  const int bk  = tid >> 3;          // 0..31  (W1 row within chunk)
  const int bc0 = (tid & 7) * 8;     // 0..56  (W1 col)

  for (int ko = 0; ko < DIN_; ko += 32) {
    float4 a0 = *(const float4*)&roles[(row_base + lr) * DIN_ + ko + lk0];
    float4 a1 = *(const float4*)&roles[(row_base + lr) * DIN_ + ko + lk0 + 4];
    s.u.p1.As[lk0 + 0][lr] = a0.x; s.u.p1.As[lk0 + 1][lr] = a0.y;
    s.u.p1.As[lk0 + 2][lr] = a0.z; s.u.p1.As[lk0 + 3][lr] = a0.w;
    s.u.p1.As[lk0 + 4][lr] = a1.x; s.u.p1.As[lk0 + 5][lr] = a1.y;
    s.u.p1.As[lk0 + 6][lr] = a1.z; s.u.p1.As[lk0 + 7][lr] = a1.w;
    float4 w0 = *(const float4*)&W1[(ko + bk) * H__ + bc0];
    float4 w1 = *(const float4*)&W1[(ko + bk) * H__ + bc0 + 4];
    *(float4*)&s.u.p1.Bs[bk][bc0]     = w0;
    *(float4*)&s.u.p1.Bs[bk][bc0 + 4] = w1;
    __syncthreads();
#pragma unroll
    for (int kk = 0; kk < 32; kk++) {
      float4 av = *(const float4*)&s.u.p1.As[kk][r0];
      float4 bv = *(const float4*)&s.u.p1.Bs[kk][c0];
      float a_[4] = {av.x, av.y, av.z, av.w};
      float b_[4] = {bv.x, bv.y, bv.z, bv.w};
#pragma unroll
      for (int i = 0; i < 4; i++)
#pragma unroll
        for (int j = 0; j < 4; j++) acc[i][j] = fmaf(a_[i], b_[j], acc[i][j]);
    }
    __syncthreads();
  }
  // bias + relu -> hT[k][r]
  {
    float4 bj = *(const float4*)&b1[c0];
    float bb[4] = {bj.x, bj.y, bj.z, bj.w};
#pragma unroll
    for (int j = 0; j < 4; j++)
#pragma unroll
      for (int i = 0; i < 4; i++)
        s.hT[c0 + j][r0 + i] = frelu(acc[i][j] + bb[j]);
  }
  __syncthreads();

  // ---------------- Phase 2a: mu, log_var, z, kld, emb ----------------
  float mu[4][4], lv[4][4];
#pragma unroll
  for (int i = 0; i < 4; i++)
#pragma unroll
    for (int j = 0; j < 4; j++) { mu[i][j] = 0.0f; lv[i][j] = 0.0f; }
  for (int k = 0; k < 64; k++) {
    float4 hv  = *(const float4*)&s.hT[k][r0];
    float4 w21 = *(const float4*)&W21[k * H__ + c0];
    float4 w22 = *(const float4*)&W22[k * H__ + c0];
    float h_[4] = {hv.x, hv.y, hv.z, hv.w};
    float a_[4] = {w21.x, w21.y, w21.z, w21.w};
    float b_[4] = {w22.x, w22.y, w22.z, w22.w};
#pragma unroll
    for (int i = 0; i < 4; i++)
#pragma unroll
      for (int j = 0; j < 4; j++) {
        mu[i][j] = fmaf(h_[i], a_[j], mu[i][j]);
        lv[i][j] = fmaf(h_[i], b_[j], lv[i][j]);
      }
  }
  const float VAR2C = (float)0.010000000000000002;   // STD2*STD2 as in ref
  const float C1    = (float)5.605170185988091;      // 1.0 - log(VAR2)
  double kacc = 0.0;
  float z[4][4];
  {
    float4 b21v = *(const float4*)&b21[c0];
    float4 b22v = *(const float4*)&b22[c0];
    float bb21[4] = {b21v.x, b21v.y, b21v.z, b21v.w};
    float bb22[4] = {b22v.x, b22v.y, b22v.z, b22v.w};
#pragma unroll
    for (int i = 0; i < 4; i++) {
      float4 ev = *(const float4*)&eps[(row_base + r0 + i) * H__ + c0];
      float e_[4] = {ev.x, ev.y, ev.z, ev.w};
#pragma unroll
      for (int j = 0; j < 4; j++) {
        float muv = mu[i][j] + bb21[j];
        float lvv = lv[i][j] + bb22[j];
        float zz  = muv + e_[j] * (expf(0.5f * lvv) * 0.1f);
        z[i][j] = zz;
        kacc += (double)((C1 + lvv) - (muv * muv + expf(lvv)) / VAR2C);
      }
    }
  }
  // row sums of z^2 and zT
#pragma unroll
  for (int i = 0; i < 4; i++) {
    float sq = 0.0f;
#pragma unroll
    for (int j = 0; j < 4; j++) {
      sq = fmaf(z[i][j], z[i][j], sq);
      s.u.zT[c0 + j][r0 + i] = z[i][j];
    }
    s.rsq[tx][r0 + i] = sq;
  }
  __syncthreads();
  if (tid < 64) {
    float t = 0.0f;
    for (int x = 0; x < 16; x++) t += s.rsq[x][tid];
    s.nrm[tid] = fmaxf(sqrtf(t), 1e-12f);
  }
  __syncthreads();
#pragma unroll
  for (int i = 0; i < 4; i++) {
    float nr = s.nrm[r0 + i];
    float4 ev;
    ev.x = z[i][0] / nr; ev.y = z[i][1] / nr;
    ev.z = z[i][2] / nr; ev.w = z[i][3] / nr;
    *(float4*)&emb[(row_base + r0 + i) * H__ + c0] = ev;
  }

  // ---------------- Phase 2b: t = relu(z @ W3 + b3) -> tT (reuse hT) ----------------
  float ta[4][4];
#pragma unroll
  for (int i = 0; i < 4; i++)
#pragma unroll
    for (int j = 0; j < 4; j++) ta[i][j] = 0.0f;
  for (int k = 0; k < 64; k++) {
    float4 zv = *(const float4*)&s.u.zT[k][r0];
    float4 wv = *(const float4*)&W3[k * H__ + c0];
    float z_[4] = {zv.x, zv.y, zv.z, zv.w};
    float w_[4] = {wv.x, wv.y, wv.z, wv.w};
#pragma unroll
    for (int i = 0; i < 4; i++)
#pragma unroll
      for (int j = 0; j < 4; j++) ta[i][j] = fmaf(z_[i], w_[j], ta[i][j]);
  }
  __syncthreads();   // everyone done reading hT (phase 2a) before overwrite
  {
    float4 b3v = *(const float4*)&b3[c0];
    float bb[4] = {b3v.x, b3v.y, b3v.z, b3v.w};
#pragma unroll
    for (int j = 0; j < 4; j++)
#pragma unroll
      for (int i = 0; i < 4; i++)
        s.hT[c0 + j][r0 + i] = frelu(ta[i][j] + bb[j]);
  }
  __syncthreads();

  // ---------------- Phase 3: x_hat = t @ W4 + b4, mse accumulation ----------------
  double macc = 0.0;
  for (int dc = 0; dc < DIN_; dc += 64) {
    float xa[4][4];
#pragma unroll
    for (int i = 0; i < 4; i++)
#pragma unroll
      for (int j = 0; j < 4; j++) xa[i][j] = 0.0f;
    for (int k = 0; k < 64; k++) {
      float4 tv = *(const float4*)&s.hT[k][r0];
      float4 wv = *(const float4*)&W4[k * DIN_ + dc + c0];
      float t_[4] = {tv.x, tv.y, tv.z, tv.w};
      float w_[4] = {wv.x, wv.y, wv.z, wv.w};
#pragma unroll
      for (int i = 0; i < 4; i++)
#pragma unroll
        for (int j = 0; j < 4; j++) xa[i][j] = fmaf(t_[i], w_[j], xa[i][j]);
    }
    float4 b4v = *(const float4*)&b4[dc + c0];
    float bb[4] = {b4v.x, b4v.y, b4v.z, b4v.w};
#pragma unroll
    for (int i = 0; i < 4; i++) {
      float4 rv = *(const float4*)&roles[(row_base + r0 + i) * DIN_ + dc + c0];
      float r_[4] = {rv.x, rv.y, rv.z, rv.w};
#pragma unroll
      for (int j = 0; j < 4; j++) {
        float d = (xa[i][j] + bb[j]) - r_[j];
        macc += (double)(d * d);
      }
    }
  }

  // ---------------- Phase 4: block reduce + atomics ----------------
  s.red[tid] = macc;
  __syncthreads();
  for (int st = 128; st > 0; st >>= 1) {
    if (tid < st) s.red[tid] += s.red[tid + st];
    __syncthreads();
  }
  if (tid == 0) atomicAdd(&sums[0], s.red[0]);
  __syncthreads();
  s.red[tid] = kacc;
  __syncthreads();
  for (int st = 128; st > 0; st >>= 1) {
    if (tid < st) s.red[tid] += s.red[tid + st];
    __syncthreads();
  }
  if (tid == 0) atomicAdd(&sums[1], s.red[0]);
}

// ---------------------------------------------------------------------------
// K2: finalize vae_loss
// ---------------------------------------------------------------------------
__global__ void finalize_kernel(const double* __restrict__ sums,
                                float* __restrict__ out) {
  double mse_total = sums[0] / ((double)NR_ * (double)DIN_);  // = sum_b mse_b
  double kld_total = -0.5 * (sums[1] / ((double)NR_ * (double)H__));
  out[512 + 32 + 2048] = (float)((mse_total + kld_total) / (double)B_);
}

// ---------------------------------------------------------------------------
// K3: sequential selection scan. 32 blocks (one per batch item), 256 threads.
// ---------------------------------------------------------------------------
__global__ __launch_bounds__(256)
void select_kernel(const float* __restrict__ emb,
                   const float* __restrict__ contexts,
                   const float* __restrict__ rand_vals,
                   const float* __restrict__ Wc, const float* __restrict__ bc,
                   const float* __restrict__ init_emb,
                   float* __restrict__ out) {
  __shared__ float hist[64], cur[64], cvec[64], ctxs[128];
  __shared__ float scores[4096];
  __shared__ double dbl[256];
  __shared__ float sred[256];
  __shared__ int seli;
  const int b = blockIdx.x, tid = threadIdx.x;
  const float* embB = emb + (size_t)b * NR_ * H__;
  float lp = 0.0f;

  if (tid < 64) { hist[tid] = init_emb[tid]; cur[tid] = init_emb[tid]; }
  if (tid < 128) ctxs[tid] = contexts[b * DCTX_ + tid];
  __syncthreads();

  for (int step = 0; step < A__; step++) {
    const float r = rand_vals[b * A__ + step];
    // layernorm(hist + cur) on wave 0
    if (tid < 64) {
      float v = hist[tid] + cur[tid];
      float sum = v;
      for (int o = 32; o > 0; o >>= 1) sum += __shfl_xor(sum, o);
      float m = sum / 64.0f;
      float d = v - m;
      float s2 = d * d;
      for (int o = 32; o > 0; o >>= 1) s2 += __shfl_xor(s2, o);
      float var = s2 / 64.0f;
      hist[tid] = d / sqrtf(var + 1e-5f);
    }
    __syncthreads();
    // c = normalize(concat(ctx, hist) @ Wc + bc)
    if (tid < 64) {
      float a = bc[tid];
      for (int k = 0; k < 128; k++) a = fmaf(ctxs[k], Wc[k * H__ + tid], a);
      for (int k = 0; k < 64; k++)  a = fmaf(hist[k], Wc[(128 + k) * H__ + tid], a);
      float q = a * a;
      for (int o = 32; o > 0; o >>= 1) q += __shfl_xor(q, o);
      float nn = fmaxf(sqrtf(q), 1e-12f);
      cvec[tid] = a / nn;
    }
    __syncthreads();
    // logits
    float dloc[16];
    float lmax = -INFINITY;
#pragma unroll
    for (int q = 0; q < 16; q++) {
      const int i = tid + q * 256;
      const float* er = embB + (size_t)i * H__;
      float dot = 0.0f;
#pragma unroll
      for (int k = 0; k < 64; k += 4) {
        float4 ev = *(const float4*)&er[k];
        dot = fmaf(ev.x, cvec[k + 0], dot);
        dot = fmaf(ev.y, cvec[k + 1], dot);
        dot = fmaf(ev.z, cvec[k + 2], dot);
        dot = fmaf(ev.w, cvec[k + 3], dot);
      }
      dloc[q] = dot;
      lmax = fmaxf(lmax, dot);
    }
    sred[tid] = lmax;
    __syncthreads();
    for (int st = 128; st > 0; st >>= 1) {
      if (tid < st) sred[tid] = fmaxf(sred[tid], sred[tid + st]);
      __syncthreads();
    }
    float gmax = sred[0];
    __syncthreads();
    float lsum = 0.0f;
#pragma unroll
    for (int q = 0; q < 16; q++) {
      float e = expf(dloc[q] - gmax);
      scores[tid + q * 256] = e;
      lsum += e;
    }
    sred[tid] = lsum;
    __syncthreads();
    for (int st = 128; st > 0; st >>= 1) {
      if (tid < st) sred[tid] += sred[tid + st];
      __syncthreads();
    }
    float denom = sred[0];
    __syncthreads();
#pragma unroll
    for (int q = 0; q < 16; q++) scores[tid + q * 256] /= denom;
    __syncthreads();
    // hierarchical cumsum in f64, find first index with cumsum > r
    float sv[16];
    double ls = 0.0;
#pragma unroll
    for (int j = 0; j < 16; j++) { sv[j] = scores[tid * 16 + j]; ls += (double)sv[j]; }
    dbl[tid] = ls;
    __syncthreads();
    if (tid == 0) {
      double base = 0.0;
      for (int t = 0; t < 256; t++) { double tmp = dbl[t]; dbl[t] = base; base += tmp; }
      seli = 0x7fffffff;
    }
    __syncthreads();
    {
      double cum = dbl[tid];
      const double rd = (double)r;
      int cand = 0x7fffffff;
#pragma unroll
      for (int j = 0; j < 16; j++) {
        cum += (double)sv[j];
        if (cand == 0x7fffffff && cum > rd) cand = tid * 16 + j;
      }
      if (cand != 0x7fffffff) atomicMin(&seli, cand);
    }
    __syncthreads();
    const int sel = (seli == 0x7fffffff) ? 0 : seli;
    if (tid == 0) {
      lp += logf(scores[sel]);
      out[b * A__ + step] = (float)sel;
    }
    if (tid < 64) cur[tid] = embB[(size_t)sel * H__ + tid];
    __syncthreads();
  }
  if (tid == 0) out[512 + b] = lp;
  if (tid < 64) out[512 + 32 + b * H__ + tid] = hist[tid];
}

// ---------------------------------------------------------------------------
extern "C" void kernel_launch(void* const* d_in, const int* in_sizes, int n_in,
                              void* d_out, int out_size, void* d_ws, size_t ws_size,
                              hipStream_t stream) {
  (void)in_sizes; (void)n_in; (void)out_size; (void)ws_size;
  const float* roles    = (const float*)d_in[0];
  const float* contexts = (const float*)d_in[1];
  const float* eps      = (const float*)d_in[2];
  const float* rand_v   = (const float*)d_in[3];
  // d_in[4] = agent_num (unused; A=16 hardcoded)
  const float* W1  = (const float*)d_in[5];
  const float* b1  = (const float*)d_in[6];
  const float* W21 = (const float*)d_in[7];
  const float* b21 = (const float*)d_in[8];
  const float* W22 = (const float*)d_in[9];
  const float* b22 = (const float*)d_in[10];
  const float* W3  = (const float*)d_in[11];
  const float* b3  = (const float*)d_in[12];
  const float* W4  = (const float*)d_in[13];
  const float* b4  = (const float*)d_in[14];
  const float* Wc  = (const float*)d_in[15];
  const float* bc  = (const float*)d_in[16];
  const float* iem = (const float*)d_in[17];
  float* out = (float*)d_out;

  double* sums = (double*)d_ws;                       // 2 doubles at offset 0
  float*  emb  = (float*)((char*)d_ws + 256);         // B*NR*H floats

  hipMemsetAsync(d_ws, 0, 256, stream);
  vae_kernel<<<(B_ * NR_) / 64, 256, 0, stream>>>(
      roles, eps, W1, b1, W21, b21, W22, b22, W3, b3, W4, b4, emb, sums);
  finalize_kernel<<<1, 1, 0, stream>>>(sums, out);
  select_kernel<<<B_, 256, 0, stream>>>(emb, contexts, rand_v, Wc, bc, iem, out);
}